// Round 2
// baseline (493.137 us; speedup 1.0000x reference)
//
#include <hip/hip_runtime.h>

typedef float f32x4 __attribute__((ext_vector_type(4)));
typedef short s16x8 __attribute__((ext_vector_type(8)));
typedef unsigned short u16;

#define BN 4
#define CC 256
#define NN 4096

static __device__ __forceinline__ u16 f2bf(float x) {
    unsigned int u = __float_as_uint(x);
    u += 0x7FFF + ((u >> 16) & 1);   // round-to-nearest-even
    return (u16)(u >> 16);
}

// ---------------------------------------------------------------------------
// Kernel 0: transpose weights.
// wT[src][c][0..7]=qw[r][c], [8..15]=kw[r][c]; wvT[a][cp][c] = wv_a[c][cp]
// ---------------------------------------------------------------------------
__global__ __launch_bounds__(256) void k_wtrans(
    const float* __restrict__ qLw, const float* __restrict__ kLw,
    const float* __restrict__ qUw, const float* __restrict__ kUw,
    const float* __restrict__ vUw, const float* __restrict__ vLw,
    float* __restrict__ wT, float* __restrict__ wvT)
{
    int a = blockIdx.x, t = threadIdx.x;
    const float* qw = a ? qUw : qLw;
    const float* kw = a ? kUw : kLw;
#pragma unroll
    for (int r = 0; r < 8; ++r) {
        wT[((size_t)a * 256 + t) * 16 + r]     = qw[r * 256 + t];
        wT[((size_t)a * 256 + t) * 16 + 8 + r] = kw[r * 256 + t];
    }
    const float* wv = a ? vLw : vUw;
    for (int cp = 0; cp < 64; ++cp)
        wvT[((size_t)a * 64 + cp) * 256 + t] = wv[(size_t)t * 64 + cp];
}

// ---------------------------------------------------------------------------
// Kernel 1: Q/K projections. qt/kt: [attend][b][n][8] fp32. Q pre-scaled by
// log2(e) so downstream score->weight uses raw exp2.
// ---------------------------------------------------------------------------
__global__ __launch_bounds__(256) void k_qkprep(
    const float* __restrict__ fL, const float* __restrict__ fU,
    const float* __restrict__ wT,
    const float* __restrict__ qLb, const float* __restrict__ kLb,
    const float* __restrict__ qUb, const float* __restrict__ kUb,
    float* __restrict__ qt, float* __restrict__ kt)
{
    int blk = blockIdx.x;
    int nc = blk & 31, b = (blk >> 5) & 3, src = blk >> 7;
    const float* f = src ? fU : fL;
    int qa = src, ka = 1 - src;
    int t = threadIdx.x;
    int nl = t & 127;
    int cs = __builtin_amdgcn_readfirstlane(t >> 7) * 128;
    int n = nc * 128 + nl;
    const float* fp = f + (size_t)b * 256 * NN + n;
    const float* wbase = wT + (size_t)src * 4096;

    float acc[16];
#pragma unroll
    for (int r = 0; r < 16; ++r) acc[r] = 0.f;

    for (int c = cs; c < cs + 128; ++c) {
        float fv = fp[(size_t)c * NN];
        const float* wr = wbase + (size_t)c * 16;   // uniform -> s_load
#pragma unroll
        for (int r = 0; r < 16; ++r) acc[r] += wr[r] * fv;
    }

    __shared__ float red[2][128][17];
    int cc = t >> 7;
#pragma unroll
    for (int r = 0; r < 16; ++r) red[cc][nl][r] = acc[r];
    __syncthreads();

    if (t < 128) {
        const float* bq = src ? qUb : qLb;
        const float* bk = src ? kUb : kLb;
        const float L2E = 1.4426950408889634f;
        int nn = nc * 128 + t;
        float vq[8], vk[8];
#pragma unroll
        for (int r = 0; r < 8; ++r) {
            vq[r] = (red[0][t][r]     + red[1][t][r]     + bq[r]) * L2E;
            vk[r] =  red[0][t][8 + r] + red[1][t][8 + r] + bk[r];
        }
        float* qo = qt + (((size_t)qa * BN + b) * NN + nn) * 8;
        float* ko = kt + (((size_t)ka * BN + b) * NN + nn) * 8;
        *(float4*)(qo)     = make_float4(vq[0], vq[1], vq[2], vq[3]);
        *(float4*)(qo + 4) = make_float4(vq[4], vq[5], vq[6], vq[7]);
        *(float4*)(ko)     = make_float4(vk[0], vk[1], vk[2], vk[3]);
        *(float4*)(ko + 4) = make_float4(vk[4], vk[5], vk[6], vk[7]);
    }
}

// ---------------------------------------------------------------------------
// Kernel 2: Z[ab][m] = sum_n exp2(q'[m].k[n]).  LDS-staged K, broadcast reads.
// grid 256 = ab(8) x mc(32); 256 thr; thread -> one m, half of n.
// ---------------------------------------------------------------------------
__global__ __launch_bounds__(256) void k_zsum(
    const float* __restrict__ qt, const float* __restrict__ kt,
    float* __restrict__ Z)
{
    int blk = blockIdx.x;
    int mc = blk & 31, ab = blk >> 5;
    int t = threadIdx.x;
    int h = t >> 7, tl = t & 127;
    int m = mc * 128 + tl;

    __shared__ float kk[2][512][8];
    __shared__ float red[2][128];

    const float* qp = qt + ((size_t)ab * NN + m) * 8;
    float4 q0 = *(const float4*)(qp);
    float4 q1 = *(const float4*)(qp + 4);
    float q[8] = {q0.x, q0.y, q0.z, q0.w, q1.x, q1.y, q1.z, q1.w};

    const float* kbase = kt + (size_t)ab * NN * 8;
    float zs = 0.f;

    for (int s = 0; s < 4; ++s) {
        __syncthreads();
#pragma unroll
        for (int jj = 0; jj < 4; ++jj) {
            int rl = tl + 128 * jj;
            const float* kr = kbase + (size_t)(h * 2048 + s * 512 + rl) * 8;
            float4 x0 = *(const float4*)kr;
            float4 x1 = *(const float4*)(kr + 4);
            *(float4*)&kk[h][rl][0] = x0;
            *(float4*)&kk[h][rl][4] = x1;
        }
        __syncthreads();
        for (int i = 0; i < 512; i += 2) {
            const float* k0 = kk[h][i];
            const float* k1 = kk[h][i + 1];
            float s0 = 0.f, s1 = 0.f;
#pragma unroll
            for (int r = 0; r < 8; ++r) { s0 += q[r] * k0[r]; s1 += q[r] * k1[r]; }
            zs += __builtin_exp2f(s0) + __builtin_exp2f(s1);
        }
    }
    red[h][tl] = zs;
    __syncthreads();
    if (t < 128)
        Z[(size_t)ab * NN + mc * 128 + t] = red[0][t] + red[1][t];
}

// ---------------------------------------------------------------------------
// Kernel 3: vp[ab][c][m] (bf16) = (grouped_conv + bias) / Z[m]
// grid 1024 = ab(8) x g(4) x mc(32); 256 thr; wave -> 16 c, lane -> 2 m.
// f read exactly once (32 KB/block).
// ---------------------------------------------------------------------------
__global__ __launch_bounds__(256) void k_vprep(
    const float* __restrict__ fL, const float* __restrict__ fU,
    const float* __restrict__ wvT,
    const float* __restrict__ vUb, const float* __restrict__ vLb,
    const float* __restrict__ Z, u16* __restrict__ vp)
{
    int blk = blockIdx.x;
    int mc = blk & 31, g = (blk >> 5) & 3, ab = blk >> 7;
    int a = ab >> 2, b = ab & 3;
    const float* f    = a ? fL : fU;
    const float* bias = a ? vLb : vUb;
    int t = threadIdx.x, l = t & 63;
    int wu = __builtin_amdgcn_readfirstlane(t >> 6);
    int m0 = mc * 128 + l * 2;

    const float* fg = f + ((size_t)b * 256 + g * 64) * NN + m0;
    const float* wq = wvT + (size_t)a * 16384 + g * 64 + wu * 16;

    float acc[16][2];
#pragma unroll
    for (int j = 0; j < 16; ++j) { acc[j][0] = 0.f; acc[j][1] = 0.f; }

    for (int cp = 0; cp < 64; ++cp) {
        float2 fv = *(const float2*)(fg + (size_t)cp * NN);
        const float* wr = wq + (size_t)cp * 256;   // wave-uniform -> s_load
        float4 w0 = *(const float4*)(wr);
        float4 w1 = *(const float4*)(wr + 4);
        float4 w2 = *(const float4*)(wr + 8);
        float4 w3 = *(const float4*)(wr + 12);
        float wv[16] = {w0.x,w0.y,w0.z,w0.w, w1.x,w1.y,w1.z,w1.w,
                        w2.x,w2.y,w2.z,w2.w, w3.x,w3.y,w3.z,w3.w};
#pragma unroll
        for (int j = 0; j < 16; ++j) {
            acc[j][0] += wv[j] * fv.x;
            acc[j][1] += wv[j] * fv.y;
        }
    }

    float2 z = *(const float2*)(Z + (size_t)ab * NN + m0);
    float zr0 = 1.f / z.x, zr1 = 1.f / z.y;
    u16* vpo = vp + ((size_t)ab * 256 + g * 64 + wu * 16) * NN + m0;
#pragma unroll
    for (int j = 0; j < 16; ++j) {
        float bj = bias[g * 64 + wu * 16 + j];
        unsigned pk = (unsigned)f2bf((acc[j][0] + bj) * zr0) |
                      ((unsigned)f2bf((acc[j][1] + bj) * zr1) << 16);
        *(unsigned*)(vpo + (size_t)j * NN) = pk;
    }
}

// ---------------------------------------------------------------------------
// Kernel 4: out = base + beta * (vp . exp2(q'^T k))
// grid 512 = nt(64) x ab(8)  [ab in low bits -> XCD-local vp slice]
// 512 thr, 8 waves = 4 c-quarters x 2 n-halves; 64-wide n tile, 32-m K-steps;
// register-prefetched A-frags + q, double-buffered LDS E.
// ---------------------------------------------------------------------------
__global__ __launch_bounds__(512, 4) void k_main(
    const float* __restrict__ fL, const float* __restrict__ fU,
    const float* __restrict__ qt, const float* __restrict__ kt,
    const u16* __restrict__ vp, const float* __restrict__ beta_p,
    float* __restrict__ out)
{
    int blk = blockIdx.x;
    int ab = blk & 7, nt = blk >> 3;
    int a = ab >> 2, b = ab & 3;
    int n0 = nt * 64;
    int t = threadIdx.x, w = t >> 6, l = t & 63;

    __shared__ u16 ebuf[2][64][40];   // [buf][n_local][m_local padded to 40]

    // ---- E-gen mapping: thread -> (2 m rows, 2 n cols)
    int em = (t & 15) * 2;        // 0..30
    int en = (t >> 4) * 2;        // 0..62
    const float* kb = kt + ((size_t)ab * NN + n0 + en) * 8;
    float kvf[2][8];
#pragma unroll
    for (int j = 0; j < 2; ++j) {
        float4 k0 = *(const float4*)(kb + (size_t)j * 8);
        float4 k1 = *(const float4*)(kb + (size_t)j * 8 + 4);
        kvf[j][0]=k0.x; kvf[j][1]=k0.y; kvf[j][2]=k0.z; kvf[j][3]=k0.w;
        kvf[j][4]=k1.x; kvf[j][5]=k1.y; kvf[j][6]=k1.z; kvf[j][7]=k1.w;
    }
    const float* qb = qt + ((size_t)ab * NN + em) * 8;

    // ---- MFMA mapping: wave -> (c quarter, n half)
    int cq = w & 3, nh = w >> 2;
    const u16* vpl = vp + ((size_t)ab * 256 + cq * 64 + (l & 15)) * NN + (l >> 4) * 8;

    f32x4 acc[4][2];
#pragma unroll
    for (int i = 0; i < 4; ++i) { acc[i][0] = (f32x4)0.f; acc[i][1] = (f32x4)0.f; }

    // ---- prologue: E(0) + A-frags(0)
    {
        float4 a0 = *(const float4*)(qb);
        float4 a1 = *(const float4*)(qb + 4);
        float4 b0 = *(const float4*)(qb + 8);
        float4 b1 = *(const float4*)(qb + 12);
        float qr0[8] = {a0.x,a0.y,a0.z,a0.w,a1.x,a1.y,a1.z,a1.w};
        float qr1[8] = {b0.x,b0.y,b0.z,b0.w,b1.x,b1.y,b1.z,b1.w};
#pragma unroll
        for (int j = 0; j < 2; ++j) {
            float s0 = 0.f, s1 = 0.f;
#pragma unroll
            for (int r = 0; r < 8; ++r) { s0 += qr0[r]*kvf[j][r]; s1 += qr1[r]*kvf[j][r]; }
            unsigned pk = (unsigned)f2bf(__builtin_exp2f(s0)) |
                          ((unsigned)f2bf(__builtin_exp2f(s1)) << 16);
            *(unsigned*)&ebuf[0][en + j][em] = pk;
        }
    }
    s16x8 afc[4];
#pragma unroll
    for (int cf = 0; cf < 4; ++cf)
        afc[cf] = *(const s16x8*)(vpl + (size_t)cf * 16 * NN);
    __syncthreads();

    for (int k = 0; k < 128; ++k) {
        int p = k & 1;
        int m1 = (k + 1) << 5;
        bool pf = (k < 127);

        // prefetch step k+1 (q rows + A-frags) — issued before MFMAs
        float4 qa0, qa1, qb0, qb1;
        s16x8 afn[4];
        if (pf) {
            const float* qp = qb + (size_t)m1 * 8;
            qa0 = *(const float4*)(qp);
            qa1 = *(const float4*)(qp + 4);
            qb0 = *(const float4*)(qp + 8);
            qb1 = *(const float4*)(qp + 12);
#pragma unroll
            for (int cf = 0; cf < 4; ++cf)
                afn[cf] = *(const s16x8*)(vpl + (size_t)cf * 16 * NN + m1);
        }

        // B-frags from LDS, then MFMA
        s16x8 bf0 = *(const s16x8*)&ebuf[p][nh * 32 + (l & 15)][(l >> 4) * 8];
        s16x8 bf1 = *(const s16x8*)&ebuf[p][nh * 32 + 16 + (l & 15)][(l >> 4) * 8];
#pragma unroll
        for (int cf = 0; cf < 4; ++cf) {
            acc[cf][0] = __builtin_amdgcn_mfma_f32_16x16x32_bf16(afc[cf], bf0, acc[cf][0], 0, 0, 0);
            acc[cf][1] = __builtin_amdgcn_mfma_f32_16x16x32_bf16(afc[cf], bf1, acc[cf][1], 0, 0, 0);
        }

        // E(k+1): compute + LDS write (other buffer)
        if (pf) {
            float qr0[8] = {qa0.x,qa0.y,qa0.z,qa0.w,qa1.x,qa1.y,qa1.z,qa1.w};
            float qr1[8] = {qb0.x,qb0.y,qb0.z,qb0.w,qb1.x,qb1.y,qb1.z,qb1.w};
#pragma unroll
            for (int j = 0; j < 2; ++j) {
                float s0 = 0.f, s1 = 0.f;
#pragma unroll
                for (int r = 0; r < 8; ++r) { s0 += qr0[r]*kvf[j][r]; s1 += qr1[r]*kvf[j][r]; }
                unsigned pk = (unsigned)f2bf(__builtin_exp2f(s0)) |
                              ((unsigned)f2bf(__builtin_exp2f(s1)) << 16);
                *(unsigned*)&ebuf[p ^ 1][en + j][em] = pk;
            }
        }
#pragma unroll
        for (int cf = 0; cf < 4; ++cf) afc[cf] = afn[cf];
        __syncthreads();
    }

    // ---- epilogue: out = base + beta*acc
    float beta = beta_p[0];
    const float* base = a ? fU : fL;
    float* op = out + (size_t)a * ((size_t)BN * CC * NN);
#pragma unroll
    for (int cf = 0; cf < 4; ++cf)
#pragma unroll
        for (int nf = 0; nf < 2; ++nf)
#pragma unroll
            for (int r = 0; r < 4; ++r) {
                int c = cq * 64 + cf * 16 + (l >> 4) * 4 + r;
                int n = n0 + nh * 32 + nf * 16 + (l & 15);
                size_t idx = ((size_t)b * CC + c) * NN + n;
                op[idx] = base[idx] + beta * acc[cf][nf][r];
            }
}

// ---------------------------------------------------------------------------
extern "C" void kernel_launch(void* const* d_in, const int* in_sizes, int n_in,
                              void* d_out, int out_size, void* d_ws, size_t ws_size,
                              hipStream_t stream) {
    const float* fL  = (const float*)d_in[0];
    const float* fU  = (const float*)d_in[1];
    const float* qLw = (const float*)d_in[2];
    const float* qLb = (const float*)d_in[3];
    const float* kUw = (const float*)d_in[4];
    const float* kUb = (const float*)d_in[5];
    const float* vUw = (const float*)d_in[6];
    const float* vUb = (const float*)d_in[7];
    const float* qUw = (const float*)d_in[8];
    const float* qUb = (const float*)d_in[9];
    const float* kLw = (const float*)d_in[10];
    const float* kLb = (const float*)d_in[11];
    const float* vLw = (const float*)d_in[12];
    const float* vLb = (const float*)d_in[13];
    const float* beta = (const float*)d_in[14];

    char* ws = (char*)d_ws;
    float* wT  = (float*)(ws);                 //  32 KB
    float* wvT = (float*)(ws + 32768);         // 128 KB
    float* qt  = (float*)(ws + 163840);        //   1 MB
    float* kt  = (float*)(ws + 1212416);       //   1 MB
    float* Z   = (float*)(ws + 2260992);       // 128 KB
    u16*   vp  = (u16*)  (ws + 2392064);       //  16 MB
    float* out = (float*)d_out;

    k_wtrans<<<2, 256, 0, stream>>>(qLw, kLw, qUw, kUw, vUw, vLw, wT, wvT);
    k_qkprep<<<256, 256, 0, stream>>>(fL, fU, wT, qLb, kLb, qUb, kUb, qt, kt);
    k_zsum<<<256, 256, 0, stream>>>(qt, kt, Z);
    k_vprep<<<1024, 256, 0, stream>>>(fL, fU, wvT, vUb, vLb, Z, vp);
    k_main<<<512, 512, 0, stream>>>(fL, fU, qt, kt, vp, beta, out);
}

// Round 3
// 264.893 us; speedup vs baseline: 1.8616x; 1.8616x over previous
//
#include <hip/hip_runtime.h>

typedef float f32x4 __attribute__((ext_vector_type(4)));
typedef short s16x8 __attribute__((ext_vector_type(8)));
typedef unsigned short u16;
typedef unsigned long long u64;

#define BN 4
#define CC 256
#define NN 4096

static __device__ __forceinline__ u16 f2bf(float x) {
    unsigned int u = __float_as_uint(x);
    u += 0x7FFF + ((u >> 16) & 1);   // round-to-nearest-even
    return (u16)(u >> 16);
}

// ---------------------------------------------------------------------------
// Kernel 0: transpose weights.
// wT[src][c][0..7]=qw[r][c], [8..15]=kw[r][c]; wvT[a][cp][c] = wv_a[c][cp]
// ---------------------------------------------------------------------------
__global__ __launch_bounds__(256) void k_wtrans(
    const float* __restrict__ qLw, const float* __restrict__ kLw,
    const float* __restrict__ qUw, const float* __restrict__ kUw,
    const float* __restrict__ vUw, const float* __restrict__ vLw,
    float* __restrict__ wT, float* __restrict__ wvT)
{
    int a = blockIdx.x, t = threadIdx.x;
    const float* qw = a ? qUw : qLw;
    const float* kw = a ? kUw : kLw;
#pragma unroll
    for (int r = 0; r < 8; ++r) {
        wT[((size_t)a * 256 + t) * 16 + r]     = qw[r * 256 + t];
        wT[((size_t)a * 256 + t) * 16 + 8 + r] = kw[r * 256 + t];
    }
    const float* wv = a ? vLw : vUw;
    for (int cp = 0; cp < 64; ++cp)
        wvT[((size_t)a * 64 + cp) * 256 + t] = wv[(size_t)t * 64 + cp];
}

// ---------------------------------------------------------------------------
// Kernel 1: Q/K projections. qt/kt: [attend][b][n][8] fp32. Q pre-scaled by
// log2(e) so downstream score->weight uses raw exp2.
// ---------------------------------------------------------------------------
__global__ __launch_bounds__(256) void k_qkprep(
    const float* __restrict__ fL, const float* __restrict__ fU,
    const float* __restrict__ wT,
    const float* __restrict__ qLb, const float* __restrict__ kLb,
    const float* __restrict__ qUb, const float* __restrict__ kUb,
    float* __restrict__ qt, float* __restrict__ kt)
{
    int blk = blockIdx.x;
    int nc = blk & 31, b = (blk >> 5) & 3, src = blk >> 7;
    const float* f = src ? fU : fL;
    int qa = src, ka = 1 - src;
    int t = threadIdx.x;
    int nl = t & 127;
    int cs = __builtin_amdgcn_readfirstlane(t >> 7) * 128;
    int n = nc * 128 + nl;
    const float* fp = f + (size_t)b * 256 * NN + n;
    const float* wbase = wT + (size_t)src * 4096;

    float acc[16];
#pragma unroll
    for (int r = 0; r < 16; ++r) acc[r] = 0.f;

    for (int c = cs; c < cs + 128; ++c) {
        float fv = fp[(size_t)c * NN];
        const float* wr = wbase + (size_t)c * 16;   // uniform -> s_load
#pragma unroll
        for (int r = 0; r < 16; ++r) acc[r] += wr[r] * fv;
    }

    __shared__ float red[2][128][17];
    int cc = t >> 7;
#pragma unroll
    for (int r = 0; r < 16; ++r) red[cc][nl][r] = acc[r];
    __syncthreads();

    if (t < 128) {
        const float* bq = src ? qUb : qLb;
        const float* bk = src ? kUb : kLb;
        const float L2E = 1.4426950408889634f;
        int nn = nc * 128 + t;
        float vq[8], vk[8];
#pragma unroll
        for (int r = 0; r < 8; ++r) {
            vq[r] = (red[0][t][r]     + red[1][t][r]     + bq[r]) * L2E;
            vk[r] =  red[0][t][8 + r] + red[1][t][8 + r] + bk[r];
        }
        float* qo = qt + (((size_t)qa * BN + b) * NN + nn) * 8;
        float* ko = kt + (((size_t)ka * BN + b) * NN + nn) * 8;
        *(float4*)(qo)     = make_float4(vq[0], vq[1], vq[2], vq[3]);
        *(float4*)(qo + 4) = make_float4(vq[4], vq[5], vq[6], vq[7]);
        *(float4*)(ko)     = make_float4(vk[0], vk[1], vk[2], vk[3]);
        *(float4*)(ko + 4) = make_float4(vk[4], vk[5], vk[6], vk[7]);
    }
}

// ---------------------------------------------------------------------------
// Kernel 2: Z[ab][m] = sum_n exp2(q'[m].k[n]).  LDS-staged K, broadcast reads.
// ---------------------------------------------------------------------------
__global__ __launch_bounds__(256) void k_zsum(
    const float* __restrict__ qt, const float* __restrict__ kt,
    float* __restrict__ Z)
{
    int blk = blockIdx.x;
    int mc = blk & 31, ab = blk >> 5;
    int t = threadIdx.x;
    int h = t >> 7, tl = t & 127;
    int m = mc * 128 + tl;

    __shared__ float kk[2][512][8];
    __shared__ float red[2][128];

    const float* qp = qt + ((size_t)ab * NN + m) * 8;
    float4 q0 = *(const float4*)(qp);
    float4 q1 = *(const float4*)(qp + 4);
    float q[8] = {q0.x, q0.y, q0.z, q0.w, q1.x, q1.y, q1.z, q1.w};

    const float* kbase = kt + (size_t)ab * NN * 8;
    float zs = 0.f;

    for (int s = 0; s < 4; ++s) {
        __syncthreads();
#pragma unroll
        for (int jj = 0; jj < 4; ++jj) {
            int rl = tl + 128 * jj;
            const float* kr = kbase + (size_t)(h * 2048 + s * 512 + rl) * 8;
            float4 x0 = *(const float4*)kr;
            float4 x1 = *(const float4*)(kr + 4);
            *(float4*)&kk[h][rl][0] = x0;
            *(float4*)&kk[h][rl][4] = x1;
        }
        __syncthreads();
        for (int i = 0; i < 512; i += 2) {
            const float* k0 = kk[h][i];
            const float* k1 = kk[h][i + 1];
            float s0 = 0.f, s1 = 0.f;
#pragma unroll
            for (int r = 0; r < 8; ++r) { s0 += q[r] * k0[r]; s1 += q[r] * k1[r]; }
            zs += __builtin_exp2f(s0) + __builtin_exp2f(s1);
        }
    }
    red[h][tl] = zs;
    __syncthreads();
    if (t < 128)
        Z[(size_t)ab * NN + mc * 128 + t] = red[0][t] + red[1][t];
}

// ---------------------------------------------------------------------------
// Kernel 3: vp tiled: vpt[ab][kstep(128)][c(256)][mi(32)] bf16
//   element (ab,c,m) at ((ab*128 + (m>>5))*256 + c)*32 + (m&31)
// value = (grouped_conv + bias) / Z[m]
// ---------------------------------------------------------------------------
__global__ __launch_bounds__(256) void k_vprep(
    const float* __restrict__ fL, const float* __restrict__ fU,
    const float* __restrict__ wvT,
    const float* __restrict__ vUb, const float* __restrict__ vLb,
    const float* __restrict__ Z, u16* __restrict__ vpt)
{
    int blk = blockIdx.x;
    int mc = blk & 31, g = (blk >> 5) & 3, ab = blk >> 7;
    int a = ab >> 2, b = ab & 3;
    const float* f    = a ? fL : fU;
    const float* bias = a ? vLb : vUb;
    int t = threadIdx.x, l = t & 63;
    int wu = __builtin_amdgcn_readfirstlane(t >> 6);
    int m0 = mc * 128 + l * 2;

    const float* fg = f + ((size_t)b * 256 + g * 64) * NN + m0;
    const float* wq = wvT + (size_t)a * 16384 + g * 64 + wu * 16;

    float acc[16][2];
#pragma unroll
    for (int j = 0; j < 16; ++j) { acc[j][0] = 0.f; acc[j][1] = 0.f; }

    for (int cp = 0; cp < 64; ++cp) {
        float2 fv = *(const float2*)(fg + (size_t)cp * NN);
        const float* wr = wq + (size_t)cp * 256;   // wave-uniform -> s_load
        float4 w0 = *(const float4*)(wr);
        float4 w1 = *(const float4*)(wr + 4);
        float4 w2 = *(const float4*)(wr + 8);
        float4 w3 = *(const float4*)(wr + 12);
        float wv[16] = {w0.x,w0.y,w0.z,w0.w, w1.x,w1.y,w1.z,w1.w,
                        w2.x,w2.y,w2.z,w2.w, w3.x,w3.y,w3.z,w3.w};
#pragma unroll
        for (int j = 0; j < 16; ++j) {
            acc[j][0] += wv[j] * fv.x;
            acc[j][1] += wv[j] * fv.y;
        }
    }

    float2 z = *(const float2*)(Z + (size_t)ab * NN + m0);
    float zr0 = 1.f / z.x, zr1 = 1.f / z.y;
    int mt = m0 >> 5, mi = m0 & 31;
    u16* vpo = vpt + (((size_t)ab * 128 + mt) * 256 + g * 64 + wu * 16) * 32 + mi;
#pragma unroll
    for (int j = 0; j < 16; ++j) {
        float bj = bias[g * 64 + wu * 16 + j];
        unsigned pk = (unsigned)f2bf((acc[j][0] + bj) * zr0) |
                      ((unsigned)f2bf((acc[j][1] + bj) * zr1) << 16);
        *(unsigned*)(vpo + (size_t)j * 32) = pk;
    }
}

// ---------------------------------------------------------------------------
// Kernel 4: out = base + beta * (vp . exp2(q'^T k))
// grid 256 = nt(32) x ab(8) [ab in low 3 bits -> XCD-local vp/qt/kt slice]
// 512 thr = 8 waves (cq 0..3 x nh 0..1); tile 256c x 128n; 32-m K-steps.
// A-frags: direct global from tiled vp (line-dense), register double-buffered.
// E: computed by all waves (wave w owns rows 4w..4w+3, scalar q), dbuf LDS.
// ---------------------------------------------------------------------------
__global__ __launch_bounds__(512, 2) void k_main(
    const float* __restrict__ fL, const float* __restrict__ fU,
    const float* __restrict__ qt, const float* __restrict__ kt,
    const u16* __restrict__ vpt, const float* __restrict__ beta_p,
    float* __restrict__ out)
{
    int blk = blockIdx.x;
    int ab = blk & 7, nt = blk >> 3;
    int a = ab >> 2, b = ab & 3;
    int n0 = nt * 128;
    int t = threadIdx.x, l = t & 63;
    int w = __builtin_amdgcn_readfirstlane(t >> 6);   // 0..7
    int cq = w & 3, nh = w >> 2;

    __shared__ u16 ebuf[2][128][40];   // [buf][n_local][m_local padded]

    // ---- persistent K columns for E-gen: n = n0 + l and n0 + l + 64
    const float* kb = kt + ((size_t)ab * NN + n0) * 8;
    float kvf[2][8];
#pragma unroll
    for (int j = 0; j < 2; ++j) {
        const float* kr = kb + (size_t)(l + 64 * j) * 8;
        float4 x0 = *(const float4*)kr;
        float4 x1 = *(const float4*)(kr + 4);
        kvf[j][0]=x0.x; kvf[j][1]=x0.y; kvf[j][2]=x0.z; kvf[j][3]=x0.w;
        kvf[j][4]=x1.x; kvf[j][5]=x1.y; kvf[j][6]=x1.z; kvf[j][7]=x1.w;
    }

    // wave-uniform q base (rows 4w..4w+3 of each step) -> scalar loads
    const float* qb = qt + (size_t)ab * NN * 8 + (size_t)w * 32;

    // A pointer into tiled vp: tile k at ab*128*8192 + k*8192
    const u16* apb = vpt + (size_t)ab * (128ull * 8192)
                   + ((size_t)cq * 64 + (l & 15)) * 32 + (size_t)(l >> 4) * 8;

    f32x4 acc[4][4];
#pragma unroll
    for (int i = 0; i < 4; ++i)
#pragma unroll
        for (int j = 0; j < 4; ++j) acc[i][j] = (f32x4)0.f;

    float qA[4][8], qB[4][8];

    auto qload = [&](float (&dst)[4][8], int ks) {
        const float* qp = qb + (size_t)ks * 256;   // 32 rows * 8 per step
#pragma unroll
        for (int i = 0; i < 4; ++i) {
            float4 x0 = *(const float4*)(qp + i * 8);
            float4 x1 = *(const float4*)(qp + i * 8 + 4);
            dst[i][0]=x0.x; dst[i][1]=x0.y; dst[i][2]=x0.z; dst[i][3]=x0.w;
            dst[i][4]=x1.x; dst[i][5]=x1.y; dst[i][6]=x1.z; dst[i][7]=x1.w;
        }
    };

    auto egen = [&](int pbuf, const float (&qv)[4][8]) {
#pragma unroll
        for (int j = 0; j < 2; ++j) {
            u64 pk = 0;
#pragma unroll
            for (int i = 0; i < 4; ++i) {
                float s = 0.f;
#pragma unroll
                for (int r = 0; r < 8; ++r) s += qv[i][r] * kvf[j][r];
                pk |= (u64)f2bf(__builtin_exp2f(s)) << (16 * i);
            }
            *(u64*)&ebuf[pbuf][l + 64 * j][w * 4] = pk;
        }
    };

    s16x8 afc[4], afn[4];

    // ---- prologue: E(0), q(1), A(0)
    qload(qA, 0);
    egen(0, qA);
    qload(qB, 1);
#pragma unroll
    for (int cf = 0; cf < 4; ++cf)
        afc[cf] = *(const s16x8*)(apb + cf * 512);
    __syncthreads();

    const u16* ap = apb;
    // 2-step unrolled main loop (static q-buffer indexing)
#pragma unroll 1
    for (int k2 = 0; k2 < 64; ++k2) {
        // ======== even step k = 2*k2: read ebuf[0], write ebuf[1], use qB
        {
            int k = 2 * k2;
            const u16* apn = ap + 8192;
#pragma unroll
            for (int cf = 0; cf < 4; ++cf)
                afn[cf] = *(const s16x8*)(apn + cf * 512);
            if (k < 126) qload(qA, k + 2);

            s16x8 bf0 = *(const s16x8*)&ebuf[0][nh * 64      + (l & 15)][(l >> 4) * 8];
            s16x8 bf1 = *(const s16x8*)&ebuf[0][nh * 64 + 16 + (l & 15)][(l >> 4) * 8];
            s16x8 bf2 = *(const s16x8*)&ebuf[0][nh * 64 + 32 + (l & 15)][(l >> 4) * 8];
            s16x8 bf3 = *(const s16x8*)&ebuf[0][nh * 64 + 48 + (l & 15)][(l >> 4) * 8];

            egen(1, qB);   // E(k+1)

#pragma unroll
            for (int cf = 0; cf < 4; ++cf) {
                acc[cf][0] = __builtin_amdgcn_mfma_f32_16x16x32_bf16(afc[cf], bf0, acc[cf][0], 0, 0, 0);
                acc[cf][1] = __builtin_amdgcn_mfma_f32_16x16x32_bf16(afc[cf], bf1, acc[cf][1], 0, 0, 0);
                acc[cf][2] = __builtin_amdgcn_mfma_f32_16x16x32_bf16(afc[cf], bf2, acc[cf][2], 0, 0, 0);
                acc[cf][3] = __builtin_amdgcn_mfma_f32_16x16x32_bf16(afc[cf], bf3, acc[cf][3], 0, 0, 0);
            }
#pragma unroll
            for (int cf = 0; cf < 4; ++cf) afc[cf] = afn[cf];
            ap = apn;
            __syncthreads();
        }
        // ======== odd step k = 2*k2+1: read ebuf[1], write ebuf[0], use qA
        {
            int k = 2 * k2 + 1;
            const u16* apn = ap + 8192;
            if (k < 127) {
#pragma unroll
                for (int cf = 0; cf < 4; ++cf)
                    afn[cf] = *(const s16x8*)(apn + cf * 512);
            }
            if (k < 126) qload(qB, k + 2);

            s16x8 bf0 = *(const s16x8*)&ebuf[1][nh * 64      + (l & 15)][(l >> 4) * 8];
            s16x8 bf1 = *(const s16x8*)&ebuf[1][nh * 64 + 16 + (l & 15)][(l >> 4) * 8];
            s16x8 bf2 = *(const s16x8*)&ebuf[1][nh * 64 + 32 + (l & 15)][(l >> 4) * 8];
            s16x8 bf3 = *(const s16x8*)&ebuf[1][nh * 64 + 48 + (l & 15)][(l >> 4) * 8];

            if (k < 127) egen(0, qA);   // E(k+1)

#pragma unroll
            for (int cf = 0; cf < 4; ++cf) {
                acc[cf][0] = __builtin_amdgcn_mfma_f32_16x16x32_bf16(afc[cf], bf0, acc[cf][0], 0, 0, 0);
                acc[cf][1] = __builtin_amdgcn_mfma_f32_16x16x32_bf16(afc[cf], bf1, acc[cf][1], 0, 0, 0);
                acc[cf][2] = __builtin_amdgcn_mfma_f32_16x16x32_bf16(afc[cf], bf2, acc[cf][2], 0, 0, 0);
                acc[cf][3] = __builtin_amdgcn_mfma_f32_16x16x32_bf16(afc[cf], bf3, acc[cf][3], 0, 0, 0);
            }
#pragma unroll
            for (int cf = 0; cf < 4; ++cf) afc[cf] = afn[cf];
            ap = apn;
            __syncthreads();
        }
    }

    // ---- epilogue: out = base + beta*acc
    float beta = beta_p[0];
    const float* base = a ? fU : fL;
    float* op = out + (size_t)a * ((size_t)BN * CC * NN);
#pragma unroll
    for (int cf = 0; cf < 4; ++cf)
#pragma unroll
        for (int nf = 0; nf < 4; ++nf)
#pragma unroll
            for (int r = 0; r < 4; ++r) {
                int c = cq * 64 + cf * 16 + (l >> 4) * 4 + r;
                int n = n0 + nh * 64 + nf * 16 + (l & 15);
                size_t idx = ((size_t)b * CC + c) * NN + n;
                op[idx] = base[idx] + beta * acc[cf][nf][r];
            }
}

// ---------------------------------------------------------------------------
extern "C" void kernel_launch(void* const* d_in, const int* in_sizes, int n_in,
                              void* d_out, int out_size, void* d_ws, size_t ws_size,
                              hipStream_t stream) {
    const float* fL  = (const float*)d_in[0];
    const float* fU  = (const float*)d_in[1];
    const float* qLw = (const float*)d_in[2];
    const float* qLb = (const float*)d_in[3];
    const float* kUw = (const float*)d_in[4];
    const float* kUb = (const float*)d_in[5];
    const float* vUw = (const float*)d_in[6];
    const float* vUb = (const float*)d_in[7];
    const float* qUw = (const float*)d_in[8];
    const float* qUb = (const float*)d_in[9];
    const float* kLw = (const float*)d_in[10];
    const float* kLb = (const float*)d_in[11];
    const float* vLw = (const float*)d_in[12];
    const float* vLb = (const float*)d_in[13];
    const float* beta = (const float*)d_in[14];

    char* ws = (char*)d_ws;
    float* wT  = (float*)(ws);                 //  32 KB
    float* wvT = (float*)(ws + 32768);         // 128 KB
    float* qt  = (float*)(ws + 163840);        //   1 MB
    float* kt  = (float*)(ws + 1212416);       //   1 MB
    float* Z   = (float*)(ws + 2260992);       // 128 KB
    u16*   vpt = (u16*)  (ws + 2392064);       //  16 MB (tiled)
    float* out = (float*)d_out;

    k_wtrans<<<2, 256, 0, stream>>>(qLw, kLw, qUw, kUw, vUw, vLw, wT, wvT);
    k_qkprep<<<256, 256, 0, stream>>>(fL, fU, wT, qLb, kLb, qUb, kUb, qt, kt);
    k_zsum<<<256, 256, 0, stream>>>(qt, kt, Z);
    k_vprep<<<1024, 256, 0, stream>>>(fL, fU, wvT, vUb, vLb, Z, vpt);
    k_main<<<256, 512, 0, stream>>>(fL, fU, qt, kt, vpt, beta, out);
}

// Round 5
// 194.331 us; speedup vs baseline: 2.5376x; 1.3631x over previous
//
#include <hip/hip_runtime.h>

typedef float f32x4 __attribute__((ext_vector_type(4)));
typedef float f32x16 __attribute__((ext_vector_type(16)));
typedef short s16x8 __attribute__((ext_vector_type(8)));
typedef unsigned short u16;
typedef unsigned long long u64;

#define BN 4
#define CC 256
#define NN 4096

static __device__ __forceinline__ u16 f2bf(float x) {
    unsigned int u = __float_as_uint(x);
    u += 0x7FFF + ((u >> 16) & 1);   // round-to-nearest-even
    return (u16)(u >> 16);
}

// ---------------------------------------------------------------------------
// Kernel 0: transpose weights.
// wT[src][c][0..7]=qw[r][c], [8..15]=kw[r][c]; wvT[a][cp][c] = wv_a[c][cp]
// ---------------------------------------------------------------------------
__global__ __launch_bounds__(256) void k_wtrans(
    const float* __restrict__ qLw, const float* __restrict__ kLw,
    const float* __restrict__ qUw, const float* __restrict__ kUw,
    const float* __restrict__ vUw, const float* __restrict__ vLw,
    float* __restrict__ wT, float* __restrict__ wvT)
{
    int a = blockIdx.x, t = threadIdx.x;
    const float* qw = a ? qUw : qLw;
    const float* kw = a ? kUw : kLw;
#pragma unroll
    for (int r = 0; r < 8; ++r) {
        wT[((size_t)a * 256 + t) * 16 + r]     = qw[r * 256 + t];
        wT[((size_t)a * 256 + t) * 16 + 8 + r] = kw[r * 256 + t];
    }
    const float* wv = a ? vLw : vUw;
    for (int cp = 0; cp < 64; ++cp)
        wvT[((size_t)a * 64 + cp) * 256 + t] = wv[(size_t)t * 64 + cp];
}

// ---------------------------------------------------------------------------
// Kernel 1: Q/K projections -> bf16. qbf/kbf: [attend][n][8] bf16.
// Q pre-scaled by log2(e) so score->weight is raw exp2.
// ---------------------------------------------------------------------------
__global__ __launch_bounds__(256) void k_qkprep(
    const float* __restrict__ fL, const float* __restrict__ fU,
    const float* __restrict__ wT,
    const float* __restrict__ qLb, const float* __restrict__ kLb,
    const float* __restrict__ qUb, const float* __restrict__ kUb,
    u16* __restrict__ qbf, u16* __restrict__ kbf)
{
    int blk = blockIdx.x;
    int nc = blk & 31, b = (blk >> 5) & 3, src = blk >> 7;
    const float* f = src ? fU : fL;
    int qa = src, ka = 1 - src;
    int t = threadIdx.x;
    int nl = t & 127;
    int cs = __builtin_amdgcn_readfirstlane(t >> 7) * 128;
    int n = nc * 128 + nl;
    const float* fp = f + (size_t)b * 256 * NN + n;
    const float* wbase = wT + (size_t)src * 4096;

    float acc[16];
#pragma unroll
    for (int r = 0; r < 16; ++r) acc[r] = 0.f;

#pragma unroll 4
    for (int c = cs; c < cs + 128; ++c) {
        float fv = fp[(size_t)c * NN];
        const float* wr = wbase + (size_t)c * 16;   // uniform -> s_load
#pragma unroll
        for (int r = 0; r < 16; ++r) acc[r] += wr[r] * fv;
    }

    __shared__ float red[2][128][17];
    int cc = t >> 7;
#pragma unroll
    for (int r = 0; r < 16; ++r) red[cc][nl][r] = acc[r];
    __syncthreads();

    if (t < 128) {
        const float* bq = src ? qUb : qLb;
        const float* bk = src ? kUb : kLb;
        const float L2E = 1.4426950408889634f;
        int nn = nc * 128 + t;
        u16 pq[8], pk[8];
#pragma unroll
        for (int r = 0; r < 8; ++r) {
            pq[r] = f2bf((red[0][t][r]     + red[1][t][r]     + bq[r]) * L2E);
            pk[r] = f2bf( red[0][t][8 + r] + red[1][t][8 + r] + bk[r]);
        }
        uint4 vq, vk;
        vq.x = pq[0] | ((unsigned)pq[1] << 16); vq.y = pq[2] | ((unsigned)pq[3] << 16);
        vq.z = pq[4] | ((unsigned)pq[5] << 16); vq.w = pq[6] | ((unsigned)pq[7] << 16);
        vk.x = pk[0] | ((unsigned)pk[1] << 16); vk.y = pk[2] | ((unsigned)pk[3] << 16);
        vk.z = pk[4] | ((unsigned)pk[5] << 16); vk.w = pk[6] | ((unsigned)pk[7] << 16);
        *(uint4*)(qbf + (((size_t)qa * BN + b) * NN + nn) * 8) = vq;
        *(uint4*)(kbf + (((size_t)ka * BN + b) * NN + nn) * 8) = vk;
    }
}

// ---------------------------------------------------------------------------
// Kernel 2: Z[ab][m] = sum_n exp2(q'[m].k[n]) via 32x32x16 MFMA.
// grid 256 = ab(8) x mt(32); 256 thr = 4 waves; wave -> 32 m rows, all n.
// ---------------------------------------------------------------------------
__global__ __launch_bounds__(256) void k_zsum(
    const u16* __restrict__ qbf, const u16* __restrict__ kbf,
    float* __restrict__ Z)
{
    int blk = blockIdx.x;
    int mt = blk & 31, ab = blk >> 5;
    int t = threadIdx.x, l = t & 63;
    int w = __builtin_amdgcn_readfirstlane(t >> 6);
    int l31 = l & 31, g2 = l >> 5;
    int m0 = mt * 128 + w * 32;

    const u16* qab = qbf + (size_t)ab * NN * 8;
    const u16* kab = kbf + (size_t)ab * NN * 8;

    // A-frag: q rows (m=l31, k=8*g2+e; g2=1 lanes are k>=8 -> zero pad)
    s16x8 af = *(const s16x8*)(qab + (size_t)(m0 + l31) * 8);
    if (g2) af = (s16x8)0;

    auto ldb = [&](int i) -> s16x8 {
        s16x8 r = *(const s16x8*)(kab + (size_t)(i * 32 + l31) * 8);
        return g2 ? (s16x8)0 : r;
    };

    float zp[16];
#pragma unroll
    for (int r = 0; r < 16; ++r) zp[r] = 0.f;

    s16x8 b0 = ldb(0), b1 = ldb(1);
#pragma unroll 1
    for (int i = 0; i < 128; ++i) {
        int nx = i + 2 < 127 ? i + 2 : 127;
        s16x8 bn = ldb(nx);
        f32x16 s = __builtin_amdgcn_mfma_f32_32x32x16_bf16(af, b0, (f32x16)0.f, 0, 0, 0);
#pragma unroll
        for (int r = 0; r < 16; ++r) zp[r] += __builtin_exp2f(s[r]);
        b0 = b1; b1 = bn;
    }

#pragma unroll
    for (int r = 0; r < 16; ++r) {
        float v = zp[r];
#pragma unroll
        for (int d = 1; d < 32; d <<= 1) v += __shfl_xor(v, d, 64);
        zp[r] = v;
    }
    if (l31 == 0) {
#pragma unroll
        for (int r = 0; r < 16; ++r) {
            int m = m0 + (r & 3) + 8 * (r >> 2) + 4 * g2;
            Z[(size_t)ab * NN + m] = zp[r];
        }
    }
}

// ---------------------------------------------------------------------------
// Kernel 3: vp tiled: vpt[ab][kstep(128)][c(256)][mi(32)] bf16
// value = (grouped_conv + bias) / Z[m]
// ---------------------------------------------------------------------------
__global__ __launch_bounds__(256) void k_vprep(
    const float* __restrict__ fL, const float* __restrict__ fU,
    const float* __restrict__ wvT,
    const float* __restrict__ vUb, const float* __restrict__ vLb,
    const float* __restrict__ Z, u16* __restrict__ vpt)
{
    int blk = blockIdx.x;
    int mc = blk & 31, g = (blk >> 5) & 3, ab = blk >> 7;
    int a = ab >> 2, b = ab & 3;
    const float* f    = a ? fL : fU;
    const float* bias = a ? vLb : vUb;
    int t = threadIdx.x, l = t & 63;
    int wu = __builtin_amdgcn_readfirstlane(t >> 6);
    int m0 = mc * 128 + l * 2;

    const float* fg = f + ((size_t)b * 256 + g * 64) * NN + m0;
    const float* wq = wvT + (size_t)a * 16384 + g * 64 + wu * 16;

    float acc[16][2];
#pragma unroll
    for (int j = 0; j < 16; ++j) { acc[j][0] = 0.f; acc[j][1] = 0.f; }

    for (int cp = 0; cp < 64; ++cp) {
        float2 fv = *(const float2*)(fg + (size_t)cp * NN);
        const float* wr = wq + (size_t)cp * 256;   // wave-uniform -> s_load
        float4 w0 = *(const float4*)(wr);
        float4 w1 = *(const float4*)(wr + 4);
        float4 w2 = *(const float4*)(wr + 8);
        float4 w3 = *(const float4*)(wr + 12);
        float wv[16] = {w0.x,w0.y,w0.z,w0.w, w1.x,w1.y,w1.z,w1.w,
                        w2.x,w2.y,w2.z,w2.w, w3.x,w3.y,w3.z,w3.w};
#pragma unroll
        for (int j = 0; j < 16; ++j) {
            acc[j][0] += wv[j] * fv.x;
            acc[j][1] += wv[j] * fv.y;
        }
    }

    float2 z = *(const float2*)(Z + (size_t)ab * NN + m0);
    float zr0 = 1.f / z.x, zr1 = 1.f / z.y;
    int mt = m0 >> 5, mi = m0 & 31;
    u16* vpo = vpt + (((size_t)ab * 128 + mt) * 256 + g * 64 + wu * 16) * 32 + mi;
#pragma unroll
    for (int j = 0; j < 16; ++j) {
        float bj = bias[g * 64 + wu * 16 + j];
        unsigned pk = (unsigned)f2bf((acc[j][0] + bj) * zr0) |
                      ((unsigned)f2bf((acc[j][1] + bj) * zr1) << 16);
        *(unsigned*)(vpo + (size_t)j * 32) = pk;
    }
}

// ---------------------------------------------------------------------------
// Kernel 4: out = base + beta * (vp . exp2(q'^T k)), E-gen on MFMA.
// grid 256 = nt(32) x ab(8); 512 thr = 8 waves; wave = 32c strip x 128n.
// Per step: 2 S-MFMA (E-gen, K=8 padded) + 16 PV MFMA; A-panel read once.
// ---------------------------------------------------------------------------
__global__ __launch_bounds__(512) void k_main(
    const float* __restrict__ fL, const float* __restrict__ fU,
    const u16* __restrict__ qbf, const u16* __restrict__ kbf,
    const u16* __restrict__ vpt, const float* __restrict__ beta_p,
    float* __restrict__ out)
{
    int blk = blockIdx.x;
    int ab = blk & 7, nt = blk >> 3;
    int a = ab >> 2, b = ab & 3;
    int n0 = nt * 128;
    int t = threadIdx.x, l = t & 63;
    int w = __builtin_amdgcn_readfirstlane(t >> 6);   // 0..7
    int c15 = l & 15, g = l >> 4;

    __shared__ u16 ebuf[2][128][40];   // [buf][n_local][m_local padded]

    const u16* qab = qbf + (size_t)ab * NN * 8;
    const u16* kab = kbf + (size_t)ab * NN * 8;

    // constant B-frag for E-gen: k-cols n = n0 + w*16 + c15 (k = 8g+e, g>0 pad)
    s16x8 bkf = *(const s16x8*)(kab + (size_t)(n0 + w * 16 + c15) * 8);
    if (g) bkf = (s16x8)0;

    // PV A-panel base: wave's 32-c strip
    const u16* apb = vpt + (size_t)ab * (128ull * 8192)
                   + (size_t)(w * 32 + c15) * 32 + g * 8;

    f32x4 acc[2][8];
#pragma unroll
    for (int i = 0; i < 2; ++i)
#pragma unroll
        for (int j = 0; j < 8; ++j) acc[i][j] = (f32x4)0.f;

    auto qld = [&](int ks, int mh) -> s16x8 {
        s16x8 r = *(const s16x8*)(qab + (size_t)(ks * 32 + mh * 16 + c15) * 8);
        return g ? (s16x8)0 : r;
    };

    // E-gen: S = q x k (2 m-halves), exp2, pack -> ebuf[pbuf]
    auto egen = [&](int pbuf, s16x8 qa0, s16x8 qa1) {
        f32x4 s0 = __builtin_amdgcn_mfma_f32_16x16x32_bf16(qa0, bkf, (f32x4)0.f, 0, 0, 0);
        f32x4 s1 = __builtin_amdgcn_mfma_f32_16x16x32_bf16(qa1, bkf, (f32x4)0.f, 0, 0, 0);
        u64 p0 = 0, p1 = 0;
#pragma unroll
        for (int r = 0; r < 4; ++r) {
            p0 |= (u64)f2bf(__builtin_exp2f(s0[r])) << (16 * r);
            p1 |= (u64)f2bf(__builtin_exp2f(s1[r])) << (16 * r);
        }
        *(u64*)&ebuf[pbuf][w * 16 + c15][4 * g]      = p0;
        *(u64*)&ebuf[pbuf][w * 16 + c15][16 + 4 * g] = p1;
    };

    // PV: 16 MFMA against ebuf[pbuf]
    auto pv = [&](int pbuf, const s16x8& a0, const s16x8& a1) {
#pragma unroll
        for (int nf = 0; nf < 8; ++nf) {
            s16x8 bf = *(const s16x8*)&ebuf[pbuf][nf * 16 + c15][8 * g];
            acc[0][nf] = __builtin_amdgcn_mfma_f32_16x16x32_bf16(a0, bf, acc[0][nf], 0, 0, 0);
            acc[1][nf] = __builtin_amdgcn_mfma_f32_16x16x32_bf16(a1, bf, acc[1][nf], 0, 0, 0);
        }
    };

    // ---- prologue: E(0); q(1), q(2); panel(0)
    {
        s16x8 z0 = qld(0, 0), z1 = qld(0, 1);
        egen(0, z0, z1);
    }
    s16x8 qa0 = qld(1, 0), qa1 = qld(1, 1);   // used at even steps
    s16x8 qb0 = qld(2, 0), qb1 = qld(2, 1);   // used at odd steps
    s16x8 af0 = *(const s16x8*)(apb);
    s16x8 af1 = *(const s16x8*)(apb + 512);
    __syncthreads();

#pragma unroll 1
    for (int k2 = 0; k2 < 64; ++k2) {
        // ======== even step k = 2*k2: pv(ebuf[0]), egen->ebuf[1] with qa
        {
            int k = 2 * k2;
            int kn = k + 1;                       // <= 127
            const u16* apn = apb + (size_t)kn * 8192;
            s16x8 an0 = *(const s16x8*)(apn);
            s16x8 an1 = *(const s16x8*)(apn + 512);
            int kq = k + 3 < 127 ? k + 3 : 127;
            s16x8 nq0 = qld(kq, 0), nq1 = qld(kq, 1);

            egen(1, qa0, qa1);
            pv(0, af0, af1);

            af0 = an0; af1 = an1;
            qa0 = nq0; qa1 = nq1;
            __syncthreads();
        }
        // ======== odd step k = 2*k2+1: pv(ebuf[1]), egen->ebuf[0] with qb
        {
            int k = 2 * k2 + 1;
            int kn = k + 1 < 127 ? k + 1 : 127;
            const u16* apn = apb + (size_t)kn * 8192;
            s16x8 an0 = *(const s16x8*)(apn);
            s16x8 an1 = *(const s16x8*)(apn + 512);
            int kq = k + 3 < 127 ? k + 3 : 127;
            s16x8 nq0 = qld(kq, 0), nq1 = qld(kq, 1);

            if (k < 127) egen(0, qb0, qb1);
            pv(1, af0, af1);

            af0 = an0; af1 = an1;
            qb0 = nq0; qb1 = nq1;
            __syncthreads();
        }
    }

    // ---- epilogue: out = base + beta*acc
    float beta = beta_p[0];
    const float* base = a ? fU : fL;
    float* op = out + (size_t)a * ((size_t)BN * CC * NN);
#pragma unroll
    for (int cf = 0; cf < 2; ++cf)
#pragma unroll
        for (int nf = 0; nf < 8; ++nf)
#pragma unroll
            for (int r = 0; r < 4; ++r) {
                int c = w * 32 + cf * 16 + g * 4 + r;
                int n = n0 + nf * 16 + c15;
                size_t idx = ((size_t)b * CC + c) * NN + n;
                op[idx] = base[idx] + beta * acc[cf][nf][r];
            }
}

// ---------------------------------------------------------------------------
extern "C" void kernel_launch(void* const* d_in, const int* in_sizes, int n_in,
                              void* d_out, int out_size, void* d_ws, size_t ws_size,
                              hipStream_t stream) {
    const float* fL  = (const float*)d_in[0];
    const float* fU  = (const float*)d_in[1];
    const float* qLw = (const float*)d_in[2];
    const float* qLb = (const float*)d_in[3];
    const float* kUw = (const float*)d_in[4];
    const float* kUb = (const float*)d_in[5];
    const float* vUw = (const float*)d_in[6];
    const float* vUb = (const float*)d_in[7];
    const float* qUw = (const float*)d_in[8];
    const float* qUb = (const float*)d_in[9];
    const float* kLw = (const float*)d_in[10];
    const float* kLb = (const float*)d_in[11];
    const float* vLw = (const float*)d_in[12];
    const float* vLb = (const float*)d_in[13];
    const float* beta = (const float*)d_in[14];

    char* ws = (char*)d_ws;
    float* wT  = (float*)(ws);                 // [0, 32768)        32 KB
    float* wvT = (float*)(ws + 32768);         // [32768, 163840)   128 KB
    u16*   qbf = (u16*)  (ws + 163840);        // [163840, 688128)  512 KB
    u16*   kbf = (u16*)  (ws + 688128);        // [688128, 1212416) 512 KB
    float* Z   = (float*)(ws + 1212416);       // [1212416, 1343488) 128 KB
    u16*   vpt = (u16*)  (ws + 1343488);       // [1343488, +16 MB)  — FIX: was overlapping Z
    float* out = (float*)d_out;

    k_wtrans<<<2, 256, 0, stream>>>(qLw, kLw, qUw, kUw, vUw, vLw, wT, wvT);
    k_qkprep<<<256, 256, 0, stream>>>(fL, fU, wT, qLb, kLb, qUb, kUb, qbf, kbf);
    k_zsum<<<256, 256, 0, stream>>>(qbf, kbf, Z);
    k_vprep<<<1024, 256, 0, stream>>>(fL, fU, wvT, vUb, vLb, Z, vpt);
    k_main<<<256, 512, 0, stream>>>(fL, fU, qbf, kbf, vpt, beta, out);
}